// Round 17
// baseline (144.430 us; speedup 1.0000x reference)
//
#include <hip/hip_runtime.h>
#include <hip/hip_bf16.h>

typedef __attribute__((ext_vector_type(8))) short short8;   // 8 bf16 = 4 VGPRs
typedef __attribute__((ext_vector_type(4))) short s16x4;
typedef __attribute__((ext_vector_type(4))) float f32x4;

constexpr int C  = 16;
constexpr int DD = 128, HH = 128, WW = 16;
constexpr int HW = HH * WW;        // 2048
constexpr int SP = DD * HW;        // 262144
constexpr int TOT = C * SP;        // 4194304

// Padded bf16 activation layout: [dp=134][hp=134][wp=20][ci=16]
constexpr int WP_ = 20, HP_ = 134, DP_ = 134;
constexpr int ROWE   = WP_ * C;        // 320 elems (640 B) per row
constexpr int PLANEE = HP_ * ROWE;     // 42880
constexpr int PADE   = DP_ * PLANEE;   // 5,745,920 elems

using gas_ptr = const __attribute__((address_space(1))) void*;
using las_ptr = __attribute__((address_space(3))) void*;

// Packed-weight layout (shorts): w1 | wch | G0 | G1 | G2
constexpr int OFF_W1  = 0;            // 5 pairs
constexpr int OFF_WCH = 5 * 512;      // 1 pair
constexpr int OFF_G0  = OFF_WCH + 512;            // 147 pairs (fused 7x7x5)
constexpr int OFF_G1  = OFF_G0 + 147 * 512;
constexpr int OFF_G2  = OFF_G1 + 147 * 512;       // G2 has w1 folded in
constexpr int WPK_TOT = OFF_G2 + 147 * 512;

__device__ __forceinline__ float bf16_to_f(short s)
{
    union { unsigned u; float f; } cv;
    cv.u = ((unsigned)(unsigned short)s) << 16;
    return cv.f;
}

// ---------------------------------------------------------------------------
// Plane-sweep fused 7x7x5 MFMA conv, NO K-split: block = 2 waves; wave dw
// fully owns output plane d = d0+dw (acc[8] = 8 rows x 16w x 16co). Phases
// sweep 8 padded planes u (dp = d0+u); wave dw computes kd = u-dw (valid in
// 7 of 8 phases; exact partition, no merge, no duplicated tap reads).
// LDS = 2 x 10 KB (one 14-row plane window, dbuf) -> 8 blocks/CU.
// VGPR budget ~105 <= 128 cap from __launch_bounds__(128,4) -> 4 waves/SIMD,
// 16 waves/CU. A-load latency covered by TLP (no Af hoist - no reg room).
// Grid = 64 dblk x 16 hb = 1024 (XCD-chunk swizzled).
// EP: 0 = write F; 2 = write F + relu-bf16 to P (t1p);
//     3 = xs mode: F read-only, P = relu(P_x1p + F + acc + bias).
// ---------------------------------------------------------------------------
template <int EP>
__global__ __launch_bounds__(128, 4)
void conv_sweep(const short* __restrict__ xp, const short* __restrict__ wpk,
                const float* __restrict__ bias, float* __restrict__ F,
                short* __restrict__ P)
{
    constexpr int NB   = 14;               // staged rows per plane (8h + 6 halo)
    constexpr int NCHP = NB * 40;          // 560 16B chunks per plane
    constexpr int STIT = 5;                // ceil(560/128)
    constexpr int BUFSZ = STIT * 128 * 16; // 10240 B

    __shared__ alignas(16) char smem[2 * BUFSZ];   // 20480 B

    // XCD-chunk swizzle (1024 % 8 == 0 -> bijective).
    const int b0   = blockIdx.x;
    const int bid  = (b0 & 7) * 128 + (b0 >> 3);
    const int dblk = bid >> 4, hb = bid & 15;
    const int d0   = dblk * 2;
    const int tid  = threadIdx.x;
    const int dw   = tid >> 6, lane = tid & 63;    // wave's output-d offset
    const int l15  = lane & 15;
    const int cih  = (lane >> 4) & 1;
    const int tsel = lane >> 5;
    const int h0   = hb * 8;
    const int hp0  = hb * 8;                       // padded row base (PH=3)

    const char* xb = (const char*)xp;
    const char* wb = (const char*)wpk;

    // Stage plane u (padded dp = d0+u), rows hp0..hp0+13: 5 loads/thread.
    auto stage = [&](int buf, int u) {
#pragma unroll
        for (int it = 0; it < STIT; ++it) {
            int chunk = it * 128 + tid;
            int cc = chunk < NCHP ? chunk : NCHP - 1;
            const char* g = xb + (size_t)((d0 + u) * PLANEE + hp0 * ROWE) * 2
                               + (size_t)cc * 16;
            void* l = (void*)(smem + buf * BUFSZ + (it * 128 + dw * 64) * 16);
            __builtin_amdgcn_global_load_lds((gas_ptr)g, (las_ptr)l, 16, 0, 0);
        }
    };

    f32x4 acc[8] = {};

    stage(0, 0);
#pragma unroll 1
    for (int u = 0; u < 8; ++u) {                  // NU = TD+KD-1 = 8 planes
        const int cur = u & 1;
        if (u + 1 < 8) {
            stage(cur ^ 1, u + 1);
            asm volatile("s_waitcnt vmcnt(5)" ::: "memory");   // cur complete
        } else {
            asm volatile("s_waitcnt vmcnt(0)" ::: "memory");
        }
        __builtin_amdgcn_s_barrier();

        const int kd = u - dw;                     // wave-uniform
        if (kd >= 0 && kd < 7) {
            const char* lb = smem + cur * BUFSZ;
#pragma unroll
            for (int kwp = 0; kwp < 3; ++kwp) {
                const int kwa = 2 * kwp;
                const int kwb_ = (2 * kwp + 1 < 5) ? 2 * kwp + 1 : 4;  // pad: A=0
                const unsigned laneoff =
                    (unsigned)((l15 + (tsel ? kwb_ : kwa)) * 32 + cih * 16);
                short8 Bf[NB];
#pragma unroll
                for (int rB = 0; rB < NB; ++rB)
                    Bf[rB] = *(const short8*)(lb + rB * 640 + laneoff);
                __builtin_amdgcn_s_setprio(1);
#pragma unroll
                for (int kh = 0; kh < 7; ++kh) {
                    const short8 a = *(const short8*)(
                        wb + (unsigned)(((kd * 7 + kh) * 3 + kwp) * 1024 + lane * 16));
#pragma unroll
                    for (int r = 0; r < 8; ++r)
                        acc[r] = __builtin_amdgcn_mfma_f32_16x16x32_bf16(
                            a, Bf[r + kh], acc[r], 0, 0, 0);
                }
                __builtin_amdgcn_s_setprio(0);
            }
        }
        __builtin_amdgcn_s_barrier();              // reads of buf[cur] done
    }

    // Epilogue: wave dw owns output plane d0+dw outright (no merge).
    const int d  = d0 + dw;
    const int cb = (lane >> 4) * 4;
    const f32x4 bv = *(const f32x4*)(bias + cb);
#pragma unroll
    for (int r = 0; r < 8; ++r) {
        const int h = h0 + r;
        const unsigned fidx = (unsigned)(((d * HH + h) * WW + l15) * C + cb);
        f32x4 val;
#pragma unroll
        for (int j = 0; j < 4; ++j) val[j] = acc[r][j] + bv[j];
        if (EP == 0) {
            *(f32x4*)(F + fidx) = val;
        } else if (EP == 2) {
            s16x4 sv;
#pragma unroll
            for (int j = 0; j < 4; ++j) {
                __hip_bfloat16 hv = __float2bfloat16(fmaxf(val[j], 0.f));
                sv[j] = *(short*)&hv;
            }
            *(s16x4*)(P + (size_t)(d + 3) * PLANEE + (h + 3) * ROWE
                      + (l15 + 2) * 16 + cb) = sv;
            *(f32x4*)(F + fidx) = val;
        } else {   // EP == 3: xs = relu(x1p + F2 + acc + bias)
            const f32x4 f2 = *(const f32x4*)(F + fidx);
            short* prow = P + (size_t)(d + 3) * PLANEE + (h + 3) * ROWE
                          + (l15 + 2) * 16 + cb;
            const s16x4 xv = *(const s16x4*)prow;
            s16x4 sv;
#pragma unroll
            for (int j = 0; j < 4; ++j) {
                const float x1 = bf16_to_f(xv[j]);
                __hip_bfloat16 hv = __float2bfloat16(fmaxf(x1 + val[j] + f2[j], 0.f));
                sv[j] = *(short*)&hv;
            }
            *(s16x4*)prow = sv;
        }
    }
}

// ---------------------------------------------------------------------------
// Small conv (w1: 3x3x1, 9 taps) producing the padded bf16 x1p only.
// ---------------------------------------------------------------------------
template <int KD, int KH, int KW, int NTAPS, bool WF, int PW>
__global__ __launch_bounds__(256, 4)
void conv_mfma(const short* __restrict__ xp, const short* __restrict__ wpk,
               const float* __restrict__ bn_g, const float* __restrict__ bn_b,
               const float* __restrict__ bn_m, const float* __restrict__ bn_v,
               int layer, float* __restrict__ F, short* __restrict__ P)
{
    constexpr int PD = (KD - 1) / 2, PH = (KH - 1) / 2, PW_ = (KW - 1) / 2;
    constexpr int NP = (NTAPS + 1) / 2;

    const int b    = blockIdx.x;
    const int d    = b >> 3, hb = b & 7;
    const int tid  = threadIdx.x;
    const int wid  = tid >> 6, lane = tid & 63;
    const int h0   = hb * 16 + wid * 4;

    const int l15  = lane & 15;
    const int cih  = (lane >> 4) & 1;
    const int tsel = lane >> 5;
    const unsigned laneoff = (unsigned)(l15 * 32 + cih * 16);

    unsigned off_r[4];
#pragma unroll
    for (int r = 0; r < 4; ++r) {
        const int h = h0 + r;
        off_r[r] = (unsigned)((((d + (3 - PD)) * HP_ + (h + (3 - PH))) * ROWE
                               + (2 - PW_) * C) * 2) + laneoff;
    }

    const char* xb = (const char*)xp;
    const char* wb = (const char*)wpk;

    f32x4 acc[4] = {};
#pragma unroll 2
    for (int p = 0; p < NP; ++p) {
        const int ta = 2 * p;
        const int tb = (2 * p + 1 < NTAPS) ? 2 * p + 1 : NTAPS - 1;
        const int kda = ta / (KH * KW), ra = ta % (KH * KW);
        const int kha = ra / KW,        kwa = ra % KW;
        const int kdb = tb / (KH * KW), rb = tb % (KH * KW);
        const int khb = rb / KW,        kwb = rb % KW;
        const unsigned toa = (unsigned)((kda * PLANEE + kha * ROWE + kwa * C) * 2);
        const unsigned tob = (unsigned)((kdb * PLANEE + khb * ROWE + kwb * C) * 2);
        const unsigned ts  = tsel ? tob : toa;

        const short8 a = *(const short8*)(wb + (unsigned)(p * 1024 + lane * 16));
#pragma unroll
        for (int r = 0; r < 4; ++r) {
            const short8 bf = *(const short8*)(xb + (off_r[r] + ts));
            acc[r] = __builtin_amdgcn_mfma_f32_16x16x32_bf16(a, bf, acc[r], 0, 0, 0);
        }
    }

    float sc[4], sh[4];
    const int cb = (lane >> 4) * 4;
    {
        const f32x4 g  = *(const f32x4*)(bn_g + layer * C + cb);
        const f32x4 be = *(const f32x4*)(bn_b + layer * C + cb);
        const f32x4 mm = *(const f32x4*)(bn_m + layer * C + cb);
        const f32x4 v  = *(const f32x4*)(bn_v + layer * C + cb);
#pragma unroll
        for (int j = 0; j < 4; ++j) { sc[j] = g[j] / sqrtf(v[j] + 1e-5f); sh[j] = be[j] - mm[j] * sc[j]; }
    }
#pragma unroll
    for (int r = 0; r < 4; ++r) {
        const int h = h0 + r;
        f32x4 val;
#pragma unroll
        for (int j = 0; j < 4; ++j) val[j] = acc[r][j] * sc[j] + sh[j];
        if (PW == 1) {
            s16x4 sv;
#pragma unroll
            for (int j = 0; j < 4; ++j) {
                __hip_bfloat16 hv = __float2bfloat16(val[j]);
                sv[j] = *(short*)&hv;
            }
            *(s16x4*)(P + (size_t)(d + 3) * PLANEE + (h + 3) * ROWE
                      + (l15 + 2) * 16 + cb) = sv;
        }
        if (WF) {
            float* dst = F + (unsigned)(((d * HH + h) * WW + l15) * C + cb);
            *(f32x4*)dst = val;
        }
    }
}

// ---------------------------------------------------------------------------
// Final: out[co][d][h][w] = relu(F1[d][h][w][co] + conv1x1(xs, wch))
// ---------------------------------------------------------------------------
__global__ __launch_bounds__(256, 4)
void final_conv(const short* __restrict__ xsp, const short* __restrict__ wpk,
                const float* __restrict__ F1, float* __restrict__ out)
{
    const int b    = blockIdx.x;
    const int d    = b >> 3, hb = b & 7;
    const int tid  = threadIdx.x;
    const int wid  = tid >> 6, lane = tid & 63;
    const int h0   = hb * 16 + wid * 4;
    const int l15  = lane & 15;
    const int cih  = (lane >> 4) & 1;
    const int cb   = (lane >> 4) * 4;
    const unsigned laneoff = (unsigned)((l15 + 2) * 32 + cih * 16);

    const char* xb = (const char*)xsp;
    const short8 a = *(const short8*)((const char*)wpk + (unsigned)(lane * 16));

#pragma unroll
    for (int r = 0; r < 4; ++r) {
        const int h = h0 + r;
        const unsigned off = (unsigned)(((size_t)(d + 3) * PLANEE + (h + 3) * ROWE) * 2)
                             + laneoff;
        const short8 bf = *(const short8*)(xb + off);
        f32x4 acc = {};
        acc = __builtin_amdgcn_mfma_f32_16x16x32_bf16(a, bf, acc, 0, 0, 0);
        const f32x4 f1 = *(const f32x4*)(F1 + (unsigned)(((d * HH + h) * WW + l15) * C + cb));
#pragma unroll
        for (int j = 0; j < 4; ++j) {
            const float v = fmaxf(acc[j] + f1[j], 0.f);
            out[(unsigned)((cb + j) * SP + d * HW + h * WW + l15)] = v;
        }
    }
}

// ---------------------------------------------------------------------------
// pack_x: x (fp32) -> padded bf16 XP, AND zero PA's halo (merged zero_halo).
// ---------------------------------------------------------------------------
__global__ __launch_bounds__(256)
void pack_x(const float* __restrict__ x, short* __restrict__ xp,
            short* __restrict__ pa)
{
    const int b  = blockIdx.x;
    const int dp = b / HP_, hp = b % HP_;
    const int t  = threadIdx.x;
    const int d  = dp - 3, h = hp - 3;
    const bool inr = ((unsigned)d < (unsigned)DD) && ((unsigned)h < (unsigned)HH);
    short* row  = xp + (unsigned)(dp * PLANEE + hp * ROWE);
    short* rowp = pa + (unsigned)(dp * PLANEE + hp * ROWE);

    const int w = t & 15, ci = t >> 4;
    float v = 0.f;
    if (inr) v = x[ci * SP + d * HW + h * WW + w];
    __hip_bfloat16 hv = __float2bfloat16(v);
    row[(w + 2) * C + ci] = *(short*)&hv;
    if (t < 64) {
        const int pi = t >> 4;
        const int wp = (pi < 2) ? pi : (16 + pi);
        row[wp * C + (t & 15)] = 0;
    }
    // PA halo init (border rows zero; interior rows: wp pads zero)
    if (!inr) {
        for (int i = t; i < ROWE; i += 256) rowp[i] = 0;
    } else if (t < 64) {
        const int pi = t >> 4;
        const int wp = (pi < 2) ? pi : (16 + pi);
        rowp[wp * C + (t & 15)] = 0;
    }
}

// ---------------------------------------------------------------------------
// pack_small: w1 (5 linear tap-pairs, raw weights) + wch (1 pair).
// ---------------------------------------------------------------------------
__global__ __launch_bounds__(256)
void pack_small(const float* __restrict__ w1, const float* __restrict__ wch,
                short* __restrict__ dst)
{
    const int b = blockIdx.x;
    const int t = threadIdx.x;
    const int l = t >> 2, jj = t & 3;
    const int co = l & 15, cih = (l >> 4) & 1, tp = l >> 5;
    unsigned out = 0;
    if (b < 5) {
        const int tap = 2 * b + tp;
#pragma unroll
        for (int s = 0; s < 2; ++s) {
            const int ci = cih * 8 + jj * 2 + s;
            const float v = (tap < 9) ? w1[(co * C + ci) * 9 + tap] : 0.f;
            __hip_bfloat16 hv = __float2bfloat16(v);
            out |= ((unsigned)*(unsigned short*)&hv) << (16 * s);
        }
        ((unsigned*)(dst + OFF_W1))[b * 256 + l * 4 + jj] = out;
    } else {
#pragma unroll
        for (int s = 0; s < 2; ++s) {
            const int ci = cih * 8 + jj * 2 + s;
            const float v = (tp == 0) ? wch[co * C + ci] : 0.f;
            __hip_bfloat16 hv = __float2bfloat16(v);
            out |= ((unsigned)*(unsigned short*)&hv) << (16 * s);
        }
        ((unsigned*)(dst + OFF_WCH))[l * 4 + jj] = out;
    }
}

// ---------------------------------------------------------------------------
// pack_fused: conv-triples collapsed into 7x7x5 fused weights, BN scale
// folded in; per-group bias = sum of BN shifts. G2 additionally absorbs
// w1*bn0 (center taps) and bn0's shift, so its conv emits x1+y1+y2+y3.
// ---------------------------------------------------------------------------
struct W9 { const float* p[9]; };

__global__ __launch_bounds__(256)
void pack_fused(W9 w, const float* __restrict__ w1,
                const float* __restrict__ bng, const float* __restrict__ bnb,
                const float* __restrict__ bnm, const float* __restrict__ bnv,
                short* __restrict__ dst, float* __restrict__ bias)
{
    constexpr int kDm[3] = {3, 5, 7}, kHm[3] = {3, 5, 7}, kWm[3] = {1, 3, 5};
    constexpr int KHWm[3] = {9, 75, 245};

    const int b = blockIdx.x;
    const int g = b / 147, pr = b % 147;
    const int row = pr / 3, kwp = pr % 3;
    const int kd = row / 7, kh = row % 7;
    const int t = threadIdx.x;
    const int l = t >> 2, jj = t & 3;
    const int co = l & 15, cih = (l >> 4) & 1, tp = l >> 5;
    const int kw = 2 * kwp + tp;

    unsigned out = 0;
#pragma unroll
    for (int s = 0; s < 2; ++s) {
        const int ci = cih * 8 + jj * 2 + s;
        float val = 0.f;
        if (kw < 5) {
#pragma unroll
            for (int m = 0; m < 3; ++m) {
                const int od = (7 - kDm[m]) / 2, oh = (7 - kHm[m]) / 2, ow = (5 - kWm[m]) / 2;
                const int rd = kd - od, rh = kh - oh, rw = kw - ow;
                if ((unsigned)rd < (unsigned)kDm[m] && (unsigned)rh < (unsigned)kHm[m]
                    && (unsigned)rw < (unsigned)kWm[m]) {
                    const int layer = g * 3 + m + 1;
                    const float sbn = bng[layer * C + co] / sqrtf(bnv[layer * C + co] + 1e-5f);
                    val += sbn * w.p[g * 3 + m][(co * C + ci) * KHWm[m]
                                               + (rd * kHm[m] + rh) * kWm[m] + rw];
                }
            }
            if (g == 2) {   // fold w1 * bn0 (3x3x1 at center offsets 2,2,2)
                const int rd = kd - 2, rh = kh - 2, rw = kw - 2;
                if ((unsigned)rd < 3u && (unsigned)rh < 3u && rw == 0) {
                    const float sbn = bng[co] / sqrtf(bnv[co] + 1e-5f);
                    val += sbn * w1[(co * C + ci) * 9 + rd * 3 + rh];
                }
            }
        }
        __hip_bfloat16 hv = __float2bfloat16(val);
        out |= ((unsigned)*(unsigned short*)&hv) << (16 * s);
    }
    ((unsigned*)(dst + OFF_G0))[(g * 147 + pr) * 256 + l * 4 + jj] = out;

    if (pr == 0 && t < 16) {
        float bsum = 0.f;
#pragma unroll
        for (int m = 0; m < 3; ++m) {
            const int layer = g * 3 + m + 1;
            const float sbn = bng[layer * C + t] / sqrtf(bnv[layer * C + t] + 1e-5f);
            bsum += bnb[layer * C + t] - bnm[layer * C + t] * sbn;
        }
        if (g == 2) {
            const float sbn = bng[t] / sqrtf(bnv[t] + 1e-5f);
            bsum += bnb[t] - bnm[t] * sbn;
        }
        bias[g * 16 + t] = bsum;
    }
}

// ---------------------------------------------------------------------------
extern "C" void kernel_launch(void* const* d_in, const int* in_sizes, int n_in,
                              void* d_out, int out_size, void* d_ws, size_t ws_size,
                              hipStream_t stream)
{
    const float* x   = (const float*)d_in[0];
    const float* w1  = (const float*)d_in[1];
    const float* wch = (const float*)d_in[8];
    const float* bng = (const float*)d_in[12];
    const float* bnb = (const float*)d_in[13];
    const float* bnm = (const float*)d_in[14];
    const float* bnv = (const float*)d_in[15];

    W9 w9;
    w9.p[0] = (const float*)d_in[2];  w9.p[1] = (const float*)d_in[3];
    w9.p[2] = (const float*)d_in[4];  w9.p[3] = (const float*)d_in[5];
    w9.p[4] = (const float*)d_in[6];  w9.p[5] = (const float*)d_in[7];
    w9.p[6] = (const float*)d_in[9];  w9.p[7] = (const float*)d_in[10];
    w9.p[8] = (const float*)d_in[11];

    short* XP   = (short*)d_ws;            // x packed -> later t1p
    short* PA   = XP + PADE;               // x1p -> xsp
    float* F1   = (float*)(PA + PADE);     // x1 + y1+y2+y3
    short* WPK  = (short*)(F1 + TOT);
    float* BIAS = (float*)(WPK + WPK_TOT); // 48 floats
    float* F2   = (float*)d_out;           // x2..x7 sum scratch; overwritten at end

    const dim3 blk(256), blk128(128);
    const dim3 pgrid(DP_ * HP_);           // 17956
    const dim3 sgrid(DD * 8);              // 1024 (small conv, final)
    const dim3 cgrid((DD / 2) * 16);       // 1024 (plane-sweep convs)

    pack_x<<<pgrid, blk, 0, stream>>>(x, XP, PA);
    pack_small<<<dim3(6), blk, 0, stream>>>(w1, wch, WPK);
    pack_fused<<<dim3(441), blk, 0, stream>>>(w9, w1, bng, bnb, bnm, bnv, WPK, BIAS);

    // PA = x1p = bf16(cbn(x, w1, 0))
    conv_mfma<3,3,1,9,false,1><<<sgrid, blk, 0, stream>>>(
        XP, WPK + OFF_W1, bng, bnb, bnm, bnv, 0, nullptr, PA);
    // F1 = x1 + y1+y2+y3   (G2 with w1 folded, over x)
    conv_sweep<0><<<cgrid, blk128, 0, stream>>>(XP, WPK + OFF_G2, BIAS + 32, F1, nullptr);
    // F2 = x2+x3+x4 (G0 over x1p); XP <- t1p = relu(F2)
    conv_sweep<2><<<cgrid, blk128, 0, stream>>>(PA, WPK + OFF_G0, BIAS + 0, F2, XP);
    // PA <- xsp = relu(x1p + F2 + (x5+x6+x7))   (G1 over t1p, xs-fused epilogue)
    conv_sweep<3><<<cgrid, blk128, 0, stream>>>(XP, WPK + OFF_G1, BIAS + 16, F2, PA);
    // out = relu(F1 + conv1x1(xs, wch)), transposed store
    final_conv<<<sgrid, blk, 0, stream>>>(PA, WPK + OFF_WCH, F1, (float*)d_out);

    (void)in_sizes; (void)n_in; (void)out_size; (void)ws_size;
}

// Round 18
// 130.669 us; speedup vs baseline: 1.1053x; 1.1053x over previous
//
#include <hip/hip_runtime.h>
#include <hip/hip_bf16.h>

typedef __attribute__((ext_vector_type(8))) short short8;   // 8 bf16 = 4 VGPRs
typedef __attribute__((ext_vector_type(4))) short s16x4;
typedef __attribute__((ext_vector_type(4))) float f32x4;

constexpr int C  = 16;
constexpr int DD = 128, HH = 128, WW = 16;
constexpr int HW = HH * WW;        // 2048
constexpr int SP = DD * HW;        // 262144
constexpr int TOT = C * SP;        // 4194304

// Padded bf16 activation layout: [dp=134][hp=134][wp=20][ci=16]
constexpr int WP_ = 20, HP_ = 134, DP_ = 134;
constexpr int ROWE   = WP_ * C;        // 320 elems (640 B) per row
constexpr int PLANEE = HP_ * ROWE;     // 42880
constexpr int PADE   = DP_ * PLANEE;   // 5,745,920 elems

using gas_ptr = const __attribute__((address_space(1))) void*;
using las_ptr = __attribute__((address_space(3))) void*;

// Packed-weight layout (shorts): w1 | wch | G0 | G1 | G2
constexpr int OFF_W1  = 0;            // 5 pairs
constexpr int OFF_WCH = 5 * 512;      // 1 pair
constexpr int OFF_G0  = OFF_WCH + 512;            // 147 pairs (fused 7x7x5)
constexpr int OFF_G1  = OFF_G0 + 147 * 512;
constexpr int OFF_G2  = OFF_G1 + 147 * 512;       // G2 has w1 folded in
constexpr int WPK_TOT = OFF_G2 + 147 * 512;

__device__ __forceinline__ float bf16_to_f(short s)
{
    union { unsigned u; float f; } cv;
    cv.u = ((unsigned)(unsigned short)s) << 16;
    return cv.f;
}

// ---------------------------------------------------------------------------
// Best-proven conv structure (round 16, 136.1 us total): LDS-staged tiled
// MFMA conv + A-fragment register hoist (Af[2][7] issued back-to-back before
// the MFMA burst -> L1/L2 latency overlapped). Block 256 thr = 4 waves =
// 2 K-split pairs (dz-parity); pair tile 2d x 8h. Grid 512, XCD-swizzled.
// 8 waves/CU; VGPR ~200 at (256,2) -- do NOT tighten (r9/r12 spills).
// EP: 0 = write F; 2 = write F + relu-bf16 to P (t1p);
//     3 = xs mode: F read-only, P = relu(P_x1p + F + acc + bias).
// ---------------------------------------------------------------------------
template <int EP>
__global__ __launch_bounds__(256, 2)
void conv_tile_lds(const short* __restrict__ xp, const short* __restrict__ wpk,
                   const float* __restrict__ bias, float* __restrict__ F,
                   short* __restrict__ P)
{
    constexpr int KD = 7, KH = 7, KW = 5;
    constexpr int PH = 3;
    constexpr int KWP = 3;
    constexpr int NUP = (2 + KD - 1) / 2;   // 4 u-pair steps
    constexpr int NB  = 8 + KH - 1;         // 14 halo rows per wave window
    constexpr int NR  = 16 + 2 * PH;        // 22 staged rows per plane
    constexpr int NCHP = NR * 40;
    constexpr int NCH  = 2 * NCHP;
    constexpr int BUFSZ = 7 * 256 * 16;
    static_assert(NCH <= 7 * 256, "stage fits in 7 iterations");

    __shared__ alignas(16) char smem[2 * BUFSZ];

    // XCD-chunk swizzle (512 % 8 == 0 -> bijective).
    const int b0   = blockIdx.x;
    const int b    = (b0 & 7) * 64 + (b0 >> 3);
    const int dblk = b >> 3, hb = b & 7;
    const int d0   = dblk * 2;
    const int tid  = threadIdx.x;
    const int wid  = tid >> 6, lane = tid & 63;
    const int pid  = wid >> 1, m = wid & 1;
    const int l15  = lane & 15;
    const int cih  = (lane >> 4) & 1;
    const int tsel = lane >> 5;

    const char* xb = (const char*)xp;
    const char* wb = (const char*)wpk;
    const int hp0  = hb * 16;               // hb*16 + (3-PH), PH=3

    auto stage = [&](int buf, int up) {
#pragma unroll
        for (int it = 0; it < 7; ++it) {
            int chunk = it * 256 + tid;
            int cc = chunk < NCH ? chunk : NCH - 1;
            int pl = (cc >= NCHP) ? 1 : 0;
            int cp = cc - pl * NCHP;
            const char* g = xb
                + (size_t)((d0 + 2 * up + pl) * PLANEE + hp0 * ROWE) * 2
                + (size_t)cp * 16;
            void* l = (void*)(smem + buf * BUFSZ + (it * 256 + wid * 64) * 16);
            __builtin_amdgcn_global_load_lds((gas_ptr)g, (las_ptr)l, 16, 0, 0);
        }
    };

    f32x4 acc[2][8] = {};

    stage(0, 0);
#pragma unroll 1
    for (int up = 0; up < NUP; ++up) {
        const int cur = up & 1;
        if (up + 1 < NUP) {
            stage(cur ^ 1, up + 1);
            asm volatile("s_waitcnt vmcnt(7)" ::: "memory");
        } else {
            asm volatile("s_waitcnt vmcnt(0)" ::: "memory");
        }
        __builtin_amdgcn_s_barrier();

        const int u = 2 * up + m;
        const char* lb = smem + cur * BUFSZ + m * (NR * 640) + pid * 8 * 640;
#pragma unroll
        for (int kwp = 0; kwp < KWP; ++kwp) {
            const int kwa = 2 * kwp;
            const int kwb_ = (2 * kwp + 1 < KW) ? 2 * kwp + 1 : KW - 1;
            const unsigned laneoff =
                (unsigned)((l15 + (tsel ? kwb_ : kwa)) * 32 + cih * 16);

            // B fragments (LDS) and A fragments (global) issued together.
            short8 Bf[NB];
#pragma unroll
            for (int rB = 0; rB < NB; ++rB)
                Bf[rB] = *(const short8*)(lb + rB * 640 + laneoff);
            short8 Af[2][7];
#pragma unroll
            for (int ad = 0; ad < 2; ++ad) {
                const int kd = u - ad;
                if (kd < 0 || kd >= KD) continue;          // wave-uniform
#pragma unroll
                for (int kh = 0; kh < KH; ++kh)
                    Af[ad][kh] = *(const short8*)(
                        wb + (unsigned)(((kd * KH + kh) * KWP + kwp) * 1024 + lane * 16));
            }

            __builtin_amdgcn_s_setprio(1);
#pragma unroll
            for (int ad = 0; ad < 2; ++ad) {
                const int kd = u - ad;
                if (kd < 0 || kd >= KD) continue;
#pragma unroll
                for (int kh = 0; kh < KH; ++kh) {
#pragma unroll
                    for (int r = 0; r < 8; ++r)
                        acc[ad][r] = __builtin_amdgcn_mfma_f32_16x16x32_bf16(
                            Af[ad][kh], Bf[r + kh], acc[ad][r], 0, 0, 0);
                }
            }
            __builtin_amdgcn_s_setprio(0);
        }
        __builtin_amdgcn_s_barrier();
    }

    // K-split merge via LDS overlay (staging drained above).
    float* mlds = (float*)smem;
    if (m == 1) {
#pragma unroll
        for (int ad = 0; ad < 2; ++ad)
#pragma unroll
            for (int r = 0; r < 8; ++r)
                *(f32x4*)&mlds[(((pid * 2 + ad) * 8 + r) * 64 + lane) * 4] = acc[ad][r];
    }
    __syncthreads();
    if (m == 1) return;
#pragma unroll
    for (int ad = 0; ad < 2; ++ad)
#pragma unroll
        for (int r = 0; r < 8; ++r) {
            const f32x4 o = *(const f32x4*)&mlds[(((pid * 2 + ad) * 8 + r) * 64 + lane) * 4];
#pragma unroll
            for (int j = 0; j < 4; ++j) acc[ad][r][j] += o[j];
        }

    const int cb = (lane >> 4) * 4;
    const f32x4 bv = *(const f32x4*)(bias + cb);
    const int h0 = hb * 16 + pid * 8;
#pragma unroll
    for (int ad = 0; ad < 2; ++ad)
#pragma unroll
        for (int r = 0; r < 8; ++r) {
            const int d = d0 + ad, h = h0 + r;
            const unsigned fidx = (unsigned)(((d * HH + h) * WW + l15) * C + cb);
            f32x4 val;
#pragma unroll
            for (int j = 0; j < 4; ++j) val[j] = acc[ad][r][j] + bv[j];
            if (EP == 0) {
                *(f32x4*)(F + fidx) = val;
            } else if (EP == 2) {
                s16x4 sv;
#pragma unroll
                for (int j = 0; j < 4; ++j) {
                    __hip_bfloat16 hv = __float2bfloat16(fmaxf(val[j], 0.f));
                    sv[j] = *(short*)&hv;
                }
                *(s16x4*)(P + (size_t)(d + 3) * PLANEE + (h + 3) * ROWE
                          + (l15 + 2) * 16 + cb) = sv;
                *(f32x4*)(F + fidx) = val;
            } else {   // EP == 3: xs = relu(x1p + F2 + acc + bias)
                const f32x4 f2 = *(const f32x4*)(F + fidx);
                short* prow = P + (size_t)(d + 3) * PLANEE + (h + 3) * ROWE
                              + (l15 + 2) * 16 + cb;
                const s16x4 xv = *(const s16x4*)prow;
                s16x4 sv;
#pragma unroll
                for (int j = 0; j < 4; ++j) {
                    const float x1 = bf16_to_f(xv[j]);
                    __hip_bfloat16 hv = __float2bfloat16(fmaxf(x1 + val[j] + f2[j], 0.f));
                    sv[j] = *(short*)&hv;
                }
                *(s16x4*)prow = sv;
            }
        }
}

// ---------------------------------------------------------------------------
// Small conv (w1: 3x3x1, 9 taps) producing the padded bf16 x1p only.
// ---------------------------------------------------------------------------
template <int KD, int KH, int KW, int NTAPS, bool WF, int PW>
__global__ __launch_bounds__(256, 4)
void conv_mfma(const short* __restrict__ xp, const short* __restrict__ wpk,
               const float* __restrict__ bn_g, const float* __restrict__ bn_b,
               const float* __restrict__ bn_m, const float* __restrict__ bn_v,
               int layer, float* __restrict__ F, short* __restrict__ P)
{
    constexpr int PD = (KD - 1) / 2, PH = (KH - 1) / 2, PW_ = (KW - 1) / 2;
    constexpr int NP = (NTAPS + 1) / 2;

    const int b    = blockIdx.x;
    const int d    = b >> 3, hb = b & 7;
    const int tid  = threadIdx.x;
    const int wid  = tid >> 6, lane = tid & 63;
    const int h0   = hb * 16 + wid * 4;

    const int l15  = lane & 15;
    const int cih  = (lane >> 4) & 1;
    const int tsel = lane >> 5;
    const unsigned laneoff = (unsigned)(l15 * 32 + cih * 16);

    unsigned off_r[4];
#pragma unroll
    for (int r = 0; r < 4; ++r) {
        const int h = h0 + r;
        off_r[r] = (unsigned)((((d + (3 - PD)) * HP_ + (h + (3 - PH))) * ROWE
                               + (2 - PW_) * C) * 2) + laneoff;
    }

    const char* xb = (const char*)xp;
    const char* wb = (const char*)wpk;

    f32x4 acc[4] = {};
#pragma unroll 2
    for (int p = 0; p < NP; ++p) {
        const int ta = 2 * p;
        const int tb = (2 * p + 1 < NTAPS) ? 2 * p + 1 : NTAPS - 1;
        const int kda = ta / (KH * KW), ra = ta % (KH * KW);
        const int kha = ra / KW,        kwa = ra % KW;
        const int kdb = tb / (KH * KW), rb = tb % (KH * KW);
        const int khb = rb / KW,        kwb = rb % KW;
        const unsigned toa = (unsigned)((kda * PLANEE + kha * ROWE + kwa * C) * 2);
        const unsigned tob = (unsigned)((kdb * PLANEE + khb * ROWE + kwb * C) * 2);
        const unsigned ts  = tsel ? tob : toa;

        const short8 a = *(const short8*)(wb + (unsigned)(p * 1024 + lane * 16));
#pragma unroll
        for (int r = 0; r < 4; ++r) {
            const short8 bf = *(const short8*)(xb + (off_r[r] + ts));
            acc[r] = __builtin_amdgcn_mfma_f32_16x16x32_bf16(a, bf, acc[r], 0, 0, 0);
        }
    }

    float sc[4], sh[4];
    const int cb = (lane >> 4) * 4;
    {
        const f32x4 g  = *(const f32x4*)(bn_g + layer * C + cb);
        const f32x4 be = *(const f32x4*)(bn_b + layer * C + cb);
        const f32x4 mm = *(const f32x4*)(bn_m + layer * C + cb);
        const f32x4 v  = *(const f32x4*)(bn_v + layer * C + cb);
#pragma unroll
        for (int j = 0; j < 4; ++j) { sc[j] = g[j] / sqrtf(v[j] + 1e-5f); sh[j] = be[j] - mm[j] * sc[j]; }
    }
#pragma unroll
    for (int r = 0; r < 4; ++r) {
        const int h = h0 + r;
        f32x4 val;
#pragma unroll
        for (int j = 0; j < 4; ++j) val[j] = acc[r][j] * sc[j] + sh[j];
        if (PW == 1) {
            s16x4 sv;
#pragma unroll
            for (int j = 0; j < 4; ++j) {
                __hip_bfloat16 hv = __float2bfloat16(val[j]);
                sv[j] = *(short*)&hv;
            }
            *(s16x4*)(P + (size_t)(d + 3) * PLANEE + (h + 3) * ROWE
                      + (l15 + 2) * 16 + cb) = sv;
        }
        if (WF) {
            float* dst = F + (unsigned)(((d * HH + h) * WW + l15) * C + cb);
            *(f32x4*)dst = val;
        }
    }
}

// ---------------------------------------------------------------------------
// Final: out[co][d][h][w] = relu(F1[d][h][w][co] + conv1x1(xs, wch))
// ---------------------------------------------------------------------------
__global__ __launch_bounds__(256, 4)
void final_conv(const short* __restrict__ xsp, const short* __restrict__ wpk,
                const float* __restrict__ F1, float* __restrict__ out)
{
    const int b    = blockIdx.x;
    const int d    = b >> 3, hb = b & 7;
    const int tid  = threadIdx.x;
    const int wid  = tid >> 6, lane = tid & 63;
    const int h0   = hb * 16 + wid * 4;
    const int l15  = lane & 15;
    const int cih  = (lane >> 4) & 1;
    const int cb   = (lane >> 4) * 4;
    const unsigned laneoff = (unsigned)((l15 + 2) * 32 + cih * 16);

    const char* xb = (const char*)xsp;
    const short8 a = *(const short8*)((const char*)wpk + (unsigned)(lane * 16));

#pragma unroll
    for (int r = 0; r < 4; ++r) {
        const int h = h0 + r;
        const unsigned off = (unsigned)(((size_t)(d + 3) * PLANEE + (h + 3) * ROWE) * 2)
                             + laneoff;
        const short8 bf = *(const short8*)(xb + off);
        f32x4 acc = {};
        acc = __builtin_amdgcn_mfma_f32_16x16x32_bf16(a, bf, acc, 0, 0, 0);
        const f32x4 f1 = *(const f32x4*)(F1 + (unsigned)(((d * HH + h) * WW + l15) * C + cb));
#pragma unroll
        for (int j = 0; j < 4; ++j) {
            const float v = fmaxf(acc[j] + f1[j], 0.f);
            out[(unsigned)((cb + j) * SP + d * HW + h * WW + l15)] = v;
        }
    }
}

// ---------------------------------------------------------------------------
// pack_x: x (fp32) -> padded bf16 XP, AND init PA's halo (merged zero_halo).
// ---------------------------------------------------------------------------
__global__ __launch_bounds__(256)
void pack_x(const float* __restrict__ x, short* __restrict__ xp,
            short* __restrict__ pa)
{
    const int b  = blockIdx.x;
    const int dp = b / HP_, hp = b % HP_;
    const int t  = threadIdx.x;
    const int d  = dp - 3, h = hp - 3;
    const bool inr = ((unsigned)d < (unsigned)DD) && ((unsigned)h < (unsigned)HH);
    short* row  = xp + (unsigned)(dp * PLANEE + hp * ROWE);
    short* rowp = pa + (unsigned)(dp * PLANEE + hp * ROWE);

    const int w = t & 15, ci = t >> 4;
    float v = 0.f;
    if (inr) v = x[ci * SP + d * HW + h * WW + w];
    __hip_bfloat16 hv = __float2bfloat16(v);
    row[(w + 2) * C + ci] = *(short*)&hv;
    if (t < 64) {
        const int pi = t >> 4;
        const int wp = (pi < 2) ? pi : (16 + pi);
        row[wp * C + (t & 15)] = 0;
    }
    if (!inr) {
        for (int i = t; i < ROWE; i += 256) rowp[i] = 0;
    } else if (t < 64) {
        const int pi = t >> 4;
        const int wp = (pi < 2) ? pi : (16 + pi);
        rowp[wp * C + (t & 15)] = 0;
    }
}

// ---------------------------------------------------------------------------
// pack_small: w1 (5 linear tap-pairs, raw weights) + wch (1 pair).
// ---------------------------------------------------------------------------
__global__ __launch_bounds__(256)
void pack_small(const float* __restrict__ w1, const float* __restrict__ wch,
                short* __restrict__ dst)
{
    const int b = blockIdx.x;
    const int t = threadIdx.x;
    const int l = t >> 2, jj = t & 3;
    const int co = l & 15, cih = (l >> 4) & 1, tp = l >> 5;
    unsigned out = 0;
    if (b < 5) {
        const int tap = 2 * b + tp;
#pragma unroll
        for (int s = 0; s < 2; ++s) {
            const int ci = cih * 8 + jj * 2 + s;
            const float v = (tap < 9) ? w1[(co * C + ci) * 9 + tap] : 0.f;
            __hip_bfloat16 hv = __float2bfloat16(v);
            out |= ((unsigned)*(unsigned short*)&hv) << (16 * s);
        }
        ((unsigned*)(dst + OFF_W1))[b * 256 + l * 4 + jj] = out;
    } else {
#pragma unroll
        for (int s = 0; s < 2; ++s) {
            const int ci = cih * 8 + jj * 2 + s;
            const float v = (tp == 0) ? wch[co * C + ci] : 0.f;
            __hip_bfloat16 hv = __float2bfloat16(v);
            out |= ((unsigned)*(unsigned short*)&hv) << (16 * s);
        }
        ((unsigned*)(dst + OFF_WCH))[l * 4 + jj] = out;
    }
}

// ---------------------------------------------------------------------------
// pack_fused: conv-triples collapsed into 7x7x5 fused weights, BN scale
// folded in; per-group bias = sum of BN shifts. G2 additionally absorbs
// w1*bn0 (center taps) and bn0's shift, so its conv emits x1+y1+y2+y3.
// ---------------------------------------------------------------------------
struct W9 { const float* p[9]; };

__global__ __launch_bounds__(256)
void pack_fused(W9 w, const float* __restrict__ w1,
                const float* __restrict__ bng, const float* __restrict__ bnb,
                const float* __restrict__ bnm, const float* __restrict__ bnv,
                short* __restrict__ dst, float* __restrict__ bias)
{
    constexpr int kDm[3] = {3, 5, 7}, kHm[3] = {3, 5, 7}, kWm[3] = {1, 3, 5};
    constexpr int KHWm[3] = {9, 75, 245};

    const int b = blockIdx.x;
    const int g = b / 147, pr = b % 147;
    const int row = pr / 3, kwp = pr % 3;
    const int kd = row / 7, kh = row % 7;
    const int t = threadIdx.x;
    const int l = t >> 2, jj = t & 3;
    const int co = l & 15, cih = (l >> 4) & 1, tp = l >> 5;
    const int kw = 2 * kwp + tp;

    unsigned out = 0;
#pragma unroll
    for (int s = 0; s < 2; ++s) {
        const int ci = cih * 8 + jj * 2 + s;
        float val = 0.f;
        if (kw < 5) {
#pragma unroll
            for (int m = 0; m < 3; ++m) {
                const int od = (7 - kDm[m]) / 2, oh = (7 - kHm[m]) / 2, ow = (5 - kWm[m]) / 2;
                const int rd = kd - od, rh = kh - oh, rw = kw - ow;
                if ((unsigned)rd < (unsigned)kDm[m] && (unsigned)rh < (unsigned)kHm[m]
                    && (unsigned)rw < (unsigned)kWm[m]) {
                    const int layer = g * 3 + m + 1;
                    const float sbn = bng[layer * C + co] / sqrtf(bnv[layer * C + co] + 1e-5f);
                    val += sbn * w.p[g * 3 + m][(co * C + ci) * KHWm[m]
                                               + (rd * kHm[m] + rh) * kWm[m] + rw];
                }
            }
            if (g == 2) {   // fold w1 * bn0 (3x3x1 at center offsets 2,2,2)
                const int rd = kd - 2, rh = kh - 2, rw = kw - 2;
                if ((unsigned)rd < 3u && (unsigned)rh < 3u && rw == 0) {
                    const float sbn = bng[co] / sqrtf(bnv[co] + 1e-5f);
                    val += sbn * w1[(co * C + ci) * 9 + rd * 3 + rh];
                }
            }
        }
        __hip_bfloat16 hv = __float2bfloat16(val);
        out |= ((unsigned)*(unsigned short*)&hv) << (16 * s);
    }
    ((unsigned*)(dst + OFF_G0))[(g * 147 + pr) * 256 + l * 4 + jj] = out;

    if (pr == 0 && t < 16) {
        float bsum = 0.f;
#pragma unroll
        for (int m = 0; m < 3; ++m) {
            const int layer = g * 3 + m + 1;
            const float sbn = bng[layer * C + t] / sqrtf(bnv[layer * C + t] + 1e-5f);
            bsum += bnb[layer * C + t] - bnm[layer * C + t] * sbn;
        }
        if (g == 2) {
            const float sbn = bng[t] / sqrtf(bnv[t] + 1e-5f);
            bsum += bnb[t] - bnm[t] * sbn;
        }
        bias[g * 16 + t] = bsum;
    }
}

// ---------------------------------------------------------------------------
extern "C" void kernel_launch(void* const* d_in, const int* in_sizes, int n_in,
                              void* d_out, int out_size, void* d_ws, size_t ws_size,
                              hipStream_t stream)
{
    const float* x   = (const float*)d_in[0];
    const float* w1  = (const float*)d_in[1];
    const float* wch = (const float*)d_in[8];
    const float* bng = (const float*)d_in[12];
    const float* bnb = (const float*)d_in[13];
    const float* bnm = (const float*)d_in[14];
    const float* bnv = (const float*)d_in[15];

    W9 w9;
    w9.p[0] = (const float*)d_in[2];  w9.p[1] = (const float*)d_in[3];
    w9.p[2] = (const float*)d_in[4];  w9.p[3] = (const float*)d_in[5];
    w9.p[4] = (const float*)d_in[6];  w9.p[5] = (const float*)d_in[7];
    w9.p[6] = (const float*)d_in[9];  w9.p[7] = (const float*)d_in[10];
    w9.p[8] = (const float*)d_in[11];

    short* XP   = (short*)d_ws;            // x packed -> later t1p
    short* PA   = XP + PADE;               // x1p -> xsp
    float* F1   = (float*)(PA + PADE);     // x1 + y1+y2+y3
    short* WPK  = (short*)(F1 + TOT);
    float* BIAS = (float*)(WPK + WPK_TOT); // 48 floats
    float* F2   = (float*)d_out;           // x2..x7 sum scratch; overwritten at end

    const dim3 blk(256);
    const dim3 pgrid(DP_ * HP_);           // 17956
    const dim3 sgrid(DD * 8);              // 1024 (small conv, final)
    const dim3 tgrid((DD / 2) * 8);        // 512  (tile convs)

    pack_x<<<pgrid, blk, 0, stream>>>(x, XP, PA);
    pack_small<<<dim3(6), blk, 0, stream>>>(w1, wch, WPK);
    pack_fused<<<dim3(441), blk, 0, stream>>>(w9, w1, bng, bnb, bnm, bnv, WPK, BIAS);

    // PA = x1p = bf16(cbn(x, w1, 0))
    conv_mfma<3,3,1,9,false,1><<<sgrid, blk, 0, stream>>>(
        XP, WPK + OFF_W1, bng, bnb, bnm, bnv, 0, nullptr, PA);
    // F1 = x1 + y1+y2+y3   (G2 with w1 folded, over x)
    conv_tile_lds<0><<<tgrid, blk, 0, stream>>>(XP, WPK + OFF_G2, BIAS + 32, F1, nullptr);
    // F2 = x2+x3+x4 (G0 over x1p); XP <- t1p = relu(F2)
    conv_tile_lds<2><<<tgrid, blk, 0, stream>>>(PA, WPK + OFF_G0, BIAS + 0, F2, XP);
    // PA <- xsp = relu(x1p + F2 + (x5+x6+x7))   (G1 over t1p, xs-fused epilogue)
    conv_tile_lds<3><<<tgrid, blk, 0, stream>>>(XP, WPK + OFF_G1, BIAS + 16, F2, PA);
    // out = relu(F1 + conv1x1(xs, wch)), transposed store
    final_conv<<<sgrid, blk, 0, stream>>>(PA, WPK + OFF_WCH, F1, (float*)d_out);

    (void)in_sizes; (void)n_in; (void)out_size; (void)ws_size;
}

// Round 19
// 127.378 us; speedup vs baseline: 1.1339x; 1.0258x over previous
//
#include <hip/hip_runtime.h>
#include <hip/hip_bf16.h>

typedef __attribute__((ext_vector_type(8))) short short8;   // 8 bf16 = 4 VGPRs
typedef __attribute__((ext_vector_type(4))) short s16x4;
typedef __attribute__((ext_vector_type(4))) float f32x4;

constexpr int C  = 16;
constexpr int DD = 128, HH = 128, WW = 16;
constexpr int HW = HH * WW;        // 2048
constexpr int SP = DD * HW;        // 262144
constexpr int TOT = C * SP;        // 4194304

// Padded bf16 activation layout: [dp=134][hp=134][wp=20][ci=16]
constexpr int WP_ = 20, HP_ = 134, DP_ = 134;
constexpr int ROWE   = WP_ * C;        // 320 elems (640 B) per row
constexpr int PLANEE = HP_ * ROWE;     // 42880
constexpr int PADE   = DP_ * PLANEE;   // 5,745,920 elems

using gas_ptr = const __attribute__((address_space(1))) void*;
using las_ptr = __attribute__((address_space(3))) void*;

// Packed-weight layout (shorts): w1 | wch | G0 | G1 | G2
constexpr int OFF_W1  = 0;            // 5 pairs
constexpr int OFF_WCH = 5 * 512;      // 1 pair
constexpr int OFF_G0  = OFF_WCH + 512;            // 147 pairs (fused 7x7x5)
constexpr int OFF_G1  = OFF_G0 + 147 * 512;
constexpr int OFF_G2  = OFF_G1 + 147 * 512;       // G2 has w1 folded in
constexpr int WPK_TOT = OFF_G2 + 147 * 512;

// conv LDS buffer size (two staged planes, dbuf)
constexpr int CONV_BUFSZ = 7 * 256 * 16;          // 28672 B

__device__ __forceinline__ float bf16_to_f(short s)
{
    union { unsigned u; float f; } cv;
    cv.u = ((unsigned)(unsigned short)s) << 16;
    return cv.f;
}

// ---------------------------------------------------------------------------
// Proven conv core (round 16/18, ~32us/dispatch): LDS-staged tiled MFMA conv
// + A-fragment register hoist. 4 waves = 2 K-split pairs (dz-parity); pair
// tile 2d x 8h. bid in [0,512). VGPR ~200 -- callers must NOT cap occupancy
// below (256,2) (r9/r12: tighter caps spill the accumulators).
// EP: 0 = write F; 2 = write F + relu-bf16 to P (t1p);
//     3 = xs mode: F read-only, P = relu(P_x1p + F + acc + bias).
// ---------------------------------------------------------------------------
template <int EP>
__device__ __forceinline__
void conv_core(int b, const short* __restrict__ xp, const short* __restrict__ wpk,
               const float* __restrict__ bias, float* __restrict__ F,
               short* __restrict__ P, char* __restrict__ smem)
{
    constexpr int KD = 7, KH = 7, KW = 5;
    constexpr int PH = 3;
    constexpr int KWP = 3;
    constexpr int NUP = (2 + KD - 1) / 2;   // 4 u-pair steps
    constexpr int NB  = 8 + KH - 1;         // 14 halo rows per wave window
    constexpr int NR  = 16 + 2 * PH;        // 22 staged rows per plane
    constexpr int NCHP = NR * 40;
    constexpr int NCH  = 2 * NCHP;

    const int dblk = b >> 3, hb = b & 7;
    const int d0   = dblk * 2;
    const int tid  = threadIdx.x;
    const int wid  = tid >> 6, lane = tid & 63;
    const int pid  = wid >> 1, m = wid & 1;
    const int l15  = lane & 15;
    const int cih  = (lane >> 4) & 1;
    const int tsel = lane >> 5;

    const char* xb = (const char*)xp;
    const char* wb = (const char*)wpk;
    const int hp0  = hb * 16;               // hb*16 + (3-PH), PH=3

    auto stage = [&](int buf, int up) {
#pragma unroll
        for (int it = 0; it < 7; ++it) {
            int chunk = it * 256 + tid;
            int cc = chunk < NCH ? chunk : NCH - 1;
            int pl = (cc >= NCHP) ? 1 : 0;
            int cp = cc - pl * NCHP;
            const char* g = xb
                + (size_t)((d0 + 2 * up + pl) * PLANEE + hp0 * ROWE) * 2
                + (size_t)cp * 16;
            void* l = (void*)(smem + buf * CONV_BUFSZ + (it * 256 + wid * 64) * 16);
            __builtin_amdgcn_global_load_lds((gas_ptr)g, (las_ptr)l, 16, 0, 0);
        }
    };

    f32x4 acc[2][8] = {};

    stage(0, 0);
#pragma unroll 1
    for (int up = 0; up < NUP; ++up) {
        const int cur = up & 1;
        if (up + 1 < NUP) {
            stage(cur ^ 1, up + 1);
            asm volatile("s_waitcnt vmcnt(7)" ::: "memory");
        } else {
            asm volatile("s_waitcnt vmcnt(0)" ::: "memory");
        }
        __builtin_amdgcn_s_barrier();

        const int u = 2 * up + m;
        const char* lb = smem + cur * CONV_BUFSZ + m * (NR * 640) + pid * 8 * 640;
#pragma unroll
        for (int kwp = 0; kwp < KWP; ++kwp) {
            const int kwa = 2 * kwp;
            const int kwb_ = (2 * kwp + 1 < KW) ? 2 * kwp + 1 : KW - 1;
            const unsigned laneoff =
                (unsigned)((l15 + (tsel ? kwb_ : kwa)) * 32 + cih * 16);

            // B fragments (LDS) and A fragments (global) issued together.
            short8 Bf[NB];
#pragma unroll
            for (int rB = 0; rB < NB; ++rB)
                Bf[rB] = *(const short8*)(lb + rB * 640 + laneoff);
            short8 Af[2][7];
#pragma unroll
            for (int ad = 0; ad < 2; ++ad) {
                const int kd = u - ad;
                if (kd < 0 || kd >= KD) continue;          // wave-uniform
#pragma unroll
                for (int kh = 0; kh < KH; ++kh)
                    Af[ad][kh] = *(const short8*)(
                        wb + (unsigned)(((kd * KH + kh) * KWP + kwp) * 1024 + lane * 16));
            }

            __builtin_amdgcn_s_setprio(1);
#pragma unroll
            for (int ad = 0; ad < 2; ++ad) {
                const int kd = u - ad;
                if (kd < 0 || kd >= KD) continue;
#pragma unroll
                for (int kh = 0; kh < KH; ++kh) {
#pragma unroll
                    for (int r = 0; r < 8; ++r)
                        acc[ad][r] = __builtin_amdgcn_mfma_f32_16x16x32_bf16(
                            Af[ad][kh], Bf[r + kh], acc[ad][r], 0, 0, 0);
                }
            }
            __builtin_amdgcn_s_setprio(0);
        }
        __builtin_amdgcn_s_barrier();
    }

    // K-split merge via LDS overlay (staging drained above).
    float* mlds = (float*)smem;
    if (m == 1) {
#pragma unroll
        for (int ad = 0; ad < 2; ++ad)
#pragma unroll
            for (int r = 0; r < 8; ++r)
                *(f32x4*)&mlds[(((pid * 2 + ad) * 8 + r) * 64 + lane) * 4] = acc[ad][r];
    }
    __syncthreads();
    if (m == 1) return;
#pragma unroll
    for (int ad = 0; ad < 2; ++ad)
#pragma unroll
        for (int r = 0; r < 8; ++r) {
            const f32x4 o = *(const f32x4*)&mlds[(((pid * 2 + ad) * 8 + r) * 64 + lane) * 4];
#pragma unroll
            for (int j = 0; j < 4; ++j) acc[ad][r][j] += o[j];
        }

    const int cb = (lane >> 4) * 4;
    const f32x4 bv = *(const f32x4*)(bias + cb);
    const int h0 = hb * 16 + pid * 8;
#pragma unroll
    for (int ad = 0; ad < 2; ++ad)
#pragma unroll
        for (int r = 0; r < 8; ++r) {
            const int d = d0 + ad, h = h0 + r;
            const unsigned fidx = (unsigned)(((d * HH + h) * WW + l15) * C + cb);
            f32x4 val;
#pragma unroll
            for (int j = 0; j < 4; ++j) val[j] = acc[ad][r][j] + bv[j];
            if (EP == 0) {
                *(f32x4*)(F + fidx) = val;
            } else if (EP == 2) {
                s16x4 sv;
#pragma unroll
                for (int j = 0; j < 4; ++j) {
                    __hip_bfloat16 hv = __float2bfloat16(fmaxf(val[j], 0.f));
                    sv[j] = *(short*)&hv;
                }
                *(s16x4*)(P + (size_t)(d + 3) * PLANEE + (h + 3) * ROWE
                          + (l15 + 2) * 16 + cb) = sv;
                *(f32x4*)(F + fidx) = val;
            } else {   // EP == 3: xs = relu(x1p + F2 + acc + bias)
                const f32x4 f2 = *(const f32x4*)(F + fidx);
                short* prow = P + (size_t)(d + 3) * PLANEE + (h + 3) * ROWE
                              + (l15 + 2) * 16 + cb;
                const s16x4 xv = *(const s16x4*)prow;
                s16x4 sv;
#pragma unroll
                for (int j = 0; j < 4; ++j) {
                    const float x1 = bf16_to_f(xv[j]);
                    __hip_bfloat16 hv = __float2bfloat16(fmaxf(x1 + val[j] + f2[j], 0.f));
                    sv[j] = *(short*)&hv;
                }
                *(s16x4*)prow = sv;
            }
        }
}

__device__ __forceinline__ int swz512(int b0)
{
    return (b0 & 7) * 64 + (b0 >> 3);      // XCD-chunk swizzle, bijective
}

template <int EP>
__global__ __launch_bounds__(256, 2)
void conv_tile_lds(const short* __restrict__ xp, const short* __restrict__ wpk,
                   const float* __restrict__ bias, float* __restrict__ F,
                   short* __restrict__ P)
{
    __shared__ alignas(16) char smem[2 * CONV_BUFSZ];
    conv_core<EP>(swz512(blockIdx.x), xp, wpk, bias, F, P, smem);
}

// Merged G0+G2 dispatch (independent convs): blocks [0,512) = G0 (EP2, t1p
// to T1P), [512,1024) = G2 (EP0 into F1). Requires T1P workspace.
__global__ __launch_bounds__(256, 2)
void conv_dual(const short* __restrict__ xpA, const short* __restrict__ wpkA,
               const float* __restrict__ biasA, float* __restrict__ FA,
               short* __restrict__ PA_,
               const short* __restrict__ xpB, const short* __restrict__ wpkB,
               const float* __restrict__ biasB, float* __restrict__ FB)
{
    __shared__ alignas(16) char smem[2 * CONV_BUFSZ];
    const int b0 = blockIdx.x;
    if (b0 < 512)
        conv_core<2>(swz512(b0), xpA, wpkA, biasA, FA, PA_, smem);
    else
        conv_core<0>(swz512(b0 - 512), xpB, wpkB, biasB, FB, nullptr, smem);
}

// ---------------------------------------------------------------------------
// Small conv (w1: 3x3x1, 9 taps) producing the padded bf16 x1p only.
// ---------------------------------------------------------------------------
template <int KD, int KH, int KW, int NTAPS, bool WF, int PW>
__global__ __launch_bounds__(256, 4)
void conv_mfma(const short* __restrict__ xp, const short* __restrict__ wpk,
               const float* __restrict__ bn_g, const float* __restrict__ bn_b,
               const float* __restrict__ bn_m, const float* __restrict__ bn_v,
               int layer, float* __restrict__ F, short* __restrict__ P)
{
    constexpr int PD = (KD - 1) / 2, PH = (KH - 1) / 2, PW_ = (KW - 1) / 2;
    constexpr int NP = (NTAPS + 1) / 2;

    const int b    = blockIdx.x;
    const int d    = b >> 3, hb = b & 7;
    const int tid  = threadIdx.x;
    const int wid  = tid >> 6, lane = tid & 63;
    const int h0   = hb * 16 + wid * 4;

    const int l15  = lane & 15;
    const int cih  = (lane >> 4) & 1;
    const int tsel = lane >> 5;
    const unsigned laneoff = (unsigned)(l15 * 32 + cih * 16);

    unsigned off_r[4];
#pragma unroll
    for (int r = 0; r < 4; ++r) {
        const int h = h0 + r;
        off_r[r] = (unsigned)((((d + (3 - PD)) * HP_ + (h + (3 - PH))) * ROWE
                               + (2 - PW_) * C) * 2) + laneoff;
    }

    const char* xb = (const char*)xp;
    const char* wb = (const char*)wpk;

    f32x4 acc[4] = {};
#pragma unroll 2
    for (int p = 0; p < NP; ++p) {
        const int ta = 2 * p;
        const int tb = (2 * p + 1 < NTAPS) ? 2 * p + 1 : NTAPS - 1;
        const int kda = ta / (KH * KW), ra = ta % (KH * KW);
        const int kha = ra / KW,        kwa = ra % KW;
        const int kdb = tb / (KH * KW), rb = tb % (KH * KW);
        const int khb = rb / KW,        kwb = rb % KW;
        const unsigned toa = (unsigned)((kda * PLANEE + kha * ROWE + kwa * C) * 2);
        const unsigned tob = (unsigned)((kdb * PLANEE + khb * ROWE + kwb * C) * 2);
        const unsigned ts  = tsel ? tob : toa;

        const short8 a = *(const short8*)(wb + (unsigned)(p * 1024 + lane * 16));
#pragma unroll
        for (int r = 0; r < 4; ++r) {
            const short8 bf = *(const short8*)(xb + (off_r[r] + ts));
            acc[r] = __builtin_amdgcn_mfma_f32_16x16x32_bf16(a, bf, acc[r], 0, 0, 0);
        }
    }

    float sc[4], sh[4];
    const int cb = (lane >> 4) * 4;
    {
        const f32x4 g  = *(const f32x4*)(bn_g + layer * C + cb);
        const f32x4 be = *(const f32x4*)(bn_b + layer * C + cb);
        const f32x4 mm = *(const f32x4*)(bn_m + layer * C + cb);
        const f32x4 v  = *(const f32x4*)(bn_v + layer * C + cb);
#pragma unroll
        for (int j = 0; j < 4; ++j) { sc[j] = g[j] / sqrtf(v[j] + 1e-5f); sh[j] = be[j] - mm[j] * sc[j]; }
    }
#pragma unroll
    for (int r = 0; r < 4; ++r) {
        const int h = h0 + r;
        f32x4 val;
#pragma unroll
        for (int j = 0; j < 4; ++j) val[j] = acc[r][j] * sc[j] + sh[j];
        if (PW == 1) {
            s16x4 sv;
#pragma unroll
            for (int j = 0; j < 4; ++j) {
                __hip_bfloat16 hv = __float2bfloat16(val[j]);
                sv[j] = *(short*)&hv;
            }
            *(s16x4*)(P + (size_t)(d + 3) * PLANEE + (h + 3) * ROWE
                      + (l15 + 2) * 16 + cb) = sv;
        }
        if (WF) {
            float* dst = F + (unsigned)(((d * HH + h) * WW + l15) * C + cb);
            *(f32x4*)dst = val;
        }
    }
}

// ---------------------------------------------------------------------------
// Final: out[co][d][h][w] = relu(F1[d][h][w][co] + conv1x1(xs, wch))
// ---------------------------------------------------------------------------
__global__ __launch_bounds__(256, 4)
void final_conv(const short* __restrict__ xsp, const short* __restrict__ wpk,
                const float* __restrict__ F1, float* __restrict__ out)
{
    const int b    = blockIdx.x;
    const int d    = b >> 3, hb = b & 7;
    const int tid  = threadIdx.x;
    const int wid  = tid >> 6, lane = tid & 63;
    const int h0   = hb * 16 + wid * 4;
    const int l15  = lane & 15;
    const int cih  = (lane >> 4) & 1;
    const int cb   = (lane >> 4) * 4;
    const unsigned laneoff = (unsigned)((l15 + 2) * 32 + cih * 16);

    const char* xb = (const char*)xsp;
    const short8 a = *(const short8*)((const char*)wpk + (unsigned)(lane * 16));

#pragma unroll
    for (int r = 0; r < 4; ++r) {
        const int h = h0 + r;
        const unsigned off = (unsigned)(((size_t)(d + 3) * PLANEE + (h + 3) * ROWE) * 2)
                             + laneoff;
        const short8 bf = *(const short8*)(xb + off);
        f32x4 acc = {};
        acc = __builtin_amdgcn_mfma_f32_16x16x32_bf16(a, bf, acc, 0, 0, 0);
        const f32x4 f1 = *(const f32x4*)(F1 + (unsigned)(((d * HH + h) * WW + l15) * C + cb));
#pragma unroll
        for (int j = 0; j < 4; ++j) {
            const float v = fmaxf(acc[j] + f1[j], 0.f);
            out[(unsigned)((cb + j) * SP + d * HW + h * WW + l15)] = v;
        }
    }
}

// ---------------------------------------------------------------------------
// pack_x: x (fp32) -> padded bf16 XP, AND init PA's halo (merged zero_halo).
// ---------------------------------------------------------------------------
__global__ __launch_bounds__(256)
void pack_x(const float* __restrict__ x, short* __restrict__ xp,
            short* __restrict__ pa)
{
    const int b  = blockIdx.x;
    const int dp = b / HP_, hp = b % HP_;
    const int t  = threadIdx.x;
    const int d  = dp - 3, h = hp - 3;
    const bool inr = ((unsigned)d < (unsigned)DD) && ((unsigned)h < (unsigned)HH);
    short* row  = xp + (unsigned)(dp * PLANEE + hp * ROWE);
    short* rowp = pa + (unsigned)(dp * PLANEE + hp * ROWE);

    const int w = t & 15, ci = t >> 4;
    float v = 0.f;
    if (inr) v = x[ci * SP + d * HW + h * WW + w];
    __hip_bfloat16 hv = __float2bfloat16(v);
    row[(w + 2) * C + ci] = *(short*)&hv;
    if (t < 64) {
        const int pi = t >> 4;
        const int wp = (pi < 2) ? pi : (16 + pi);
        row[wp * C + (t & 15)] = 0;
    }
    if (!inr) {
        for (int i = t; i < ROWE; i += 256) rowp[i] = 0;
    } else if (t < 64) {
        const int pi = t >> 4;
        const int wp = (pi < 2) ? pi : (16 + pi);
        rowp[wp * C + (t & 15)] = 0;
    }
}

// Same as above but also inits a second padded buffer's halo (T1P).
__global__ __launch_bounds__(256)
void pack_x2(const float* __restrict__ x, short* __restrict__ xp,
             short* __restrict__ pa, short* __restrict__ t1p)
{
    const int b  = blockIdx.x;
    const int dp = b / HP_, hp = b % HP_;
    const int t  = threadIdx.x;
    const int d  = dp - 3, h = hp - 3;
    const bool inr = ((unsigned)d < (unsigned)DD) && ((unsigned)h < (unsigned)HH);
    short* row  = xp  + (unsigned)(dp * PLANEE + hp * ROWE);
    short* rowp = pa  + (unsigned)(dp * PLANEE + hp * ROWE);
    short* rowt = t1p + (unsigned)(dp * PLANEE + hp * ROWE);

    const int w = t & 15, ci = t >> 4;
    float v = 0.f;
    if (inr) v = x[ci * SP + d * HW + h * WW + w];
    __hip_bfloat16 hv = __float2bfloat16(v);
    row[(w + 2) * C + ci] = *(short*)&hv;
    if (t < 64) {
        const int pi = t >> 4;
        const int wp = (pi < 2) ? pi : (16 + pi);
        row[wp * C + (t & 15)] = 0;
    }
    if (!inr) {
        for (int i = t; i < ROWE; i += 256) { rowp[i] = 0; rowt[i] = 0; }
    } else if (t < 64) {
        const int pi = t >> 4;
        const int wp = (pi < 2) ? pi : (16 + pi);
        rowp[wp * C + (t & 15)] = 0;
        rowt[wp * C + (t & 15)] = 0;
    }
}

// ---------------------------------------------------------------------------
// pack_small: w1 (5 linear tap-pairs, raw weights) + wch (1 pair).
// ---------------------------------------------------------------------------
__global__ __launch_bounds__(256)
void pack_small(const float* __restrict__ w1, const float* __restrict__ wch,
                short* __restrict__ dst)
{
    const int b = blockIdx.x;
    const int t = threadIdx.x;
    const int l = t >> 2, jj = t & 3;
    const int co = l & 15, cih = (l >> 4) & 1, tp = l >> 5;
    unsigned out = 0;
    if (b < 5) {
        const int tap = 2 * b + tp;
#pragma unroll
        for (int s = 0; s < 2; ++s) {
            const int ci = cih * 8 + jj * 2 + s;
            const float v = (tap < 9) ? w1[(co * C + ci) * 9 + tap] : 0.f;
            __hip_bfloat16 hv = __float2bfloat16(v);
            out |= ((unsigned)*(unsigned short*)&hv) << (16 * s);
        }
        ((unsigned*)(dst + OFF_W1))[b * 256 + l * 4 + jj] = out;
    } else {
#pragma unroll
        for (int s = 0; s < 2; ++s) {
            const int ci = cih * 8 + jj * 2 + s;
            const float v = (tp == 0) ? wch[co * C + ci] : 0.f;
            __hip_bfloat16 hv = __float2bfloat16(v);
            out |= ((unsigned)*(unsigned short*)&hv) << (16 * s);
        }
        ((unsigned*)(dst + OFF_WCH))[l * 4 + jj] = out;
    }
}

// ---------------------------------------------------------------------------
// pack_fused: conv-triples collapsed into 7x7x5 fused weights, BN scale
// folded in; per-group bias = sum of BN shifts. G2 additionally absorbs
// w1*bn0 (center taps) and bn0's shift, so its conv emits x1+y1+y2+y3.
// ---------------------------------------------------------------------------
struct W9 { const float* p[9]; };

__global__ __launch_bounds__(256)
void pack_fused(W9 w, const float* __restrict__ w1,
                const float* __restrict__ bng, const float* __restrict__ bnb,
                const float* __restrict__ bnm, const float* __restrict__ bnv,
                short* __restrict__ dst, float* __restrict__ bias)
{
    constexpr int kDm[3] = {3, 5, 7}, kHm[3] = {3, 5, 7}, kWm[3] = {1, 3, 5};
    constexpr int KHWm[3] = {9, 75, 245};

    const int b = blockIdx.x;
    const int g = b / 147, pr = b % 147;
    const int row = pr / 3, kwp = pr % 3;
    const int kd = row / 7, kh = row % 7;
    const int t = threadIdx.x;
    const int l = t >> 2, jj = t & 3;
    const int co = l & 15, cih = (l >> 4) & 1, tp = l >> 5;
    const int kw = 2 * kwp + tp;

    unsigned out = 0;
#pragma unroll
    for (int s = 0; s < 2; ++s) {
        const int ci = cih * 8 + jj * 2 + s;
        float val = 0.f;
        if (kw < 5) {
#pragma unroll
            for (int m = 0; m < 3; ++m) {
                const int od = (7 - kDm[m]) / 2, oh = (7 - kHm[m]) / 2, ow = (5 - kWm[m]) / 2;
                const int rd = kd - od, rh = kh - oh, rw = kw - ow;
                if ((unsigned)rd < (unsigned)kDm[m] && (unsigned)rh < (unsigned)kHm[m]
                    && (unsigned)rw < (unsigned)kWm[m]) {
                    const int layer = g * 3 + m + 1;
                    const float sbn = bng[layer * C + co] / sqrtf(bnv[layer * C + co] + 1e-5f);
                    val += sbn * w.p[g * 3 + m][(co * C + ci) * KHWm[m]
                                               + (rd * kHm[m] + rh) * kWm[m] + rw];
                }
            }
            if (g == 2) {   // fold w1 * bn0 (3x3x1 at center offsets 2,2,2)
                const int rd = kd - 2, rh = kh - 2, rw = kw - 2;
                if ((unsigned)rd < 3u && (unsigned)rh < 3u && rw == 0) {
                    const float sbn = bng[co] / sqrtf(bnv[co] + 1e-5f);
                    val += sbn * w1[(co * C + ci) * 9 + rd * 3 + rh];
                }
            }
        }
        __hip_bfloat16 hv = __float2bfloat16(val);
        out |= ((unsigned)*(unsigned short*)&hv) << (16 * s);
    }
    ((unsigned*)(dst + OFF_G0))[(g * 147 + pr) * 256 + l * 4 + jj] = out;

    if (pr == 0 && t < 16) {
        float bsum = 0.f;
#pragma unroll
        for (int m = 0; m < 3; ++m) {
            const int layer = g * 3 + m + 1;
            const float sbn = bng[layer * C + t] / sqrtf(bnv[layer * C + t] + 1e-5f);
            bsum += bnb[layer * C + t] - bnm[layer * C + t] * sbn;
        }
        if (g == 2) {
            const float sbn = bng[t] / sqrtf(bnv[t] + 1e-5f);
            bsum += bnb[t] - bnm[t] * sbn;
        }
        bias[g * 16 + t] = bsum;
    }
}

// ---------------------------------------------------------------------------
extern "C" void kernel_launch(void* const* d_in, const int* in_sizes, int n_in,
                              void* d_out, int out_size, void* d_ws, size_t ws_size,
                              hipStream_t stream)
{
    const float* x   = (const float*)d_in[0];
    const float* w1  = (const float*)d_in[1];
    const float* wch = (const float*)d_in[8];
    const float* bng = (const float*)d_in[12];
    const float* bnb = (const float*)d_in[13];
    const float* bnm = (const float*)d_in[14];
    const float* bnv = (const float*)d_in[15];

    W9 w9;
    w9.p[0] = (const float*)d_in[2];  w9.p[1] = (const float*)d_in[3];
    w9.p[2] = (const float*)d_in[4];  w9.p[3] = (const float*)d_in[5];
    w9.p[4] = (const float*)d_in[6];  w9.p[5] = (const float*)d_in[7];
    w9.p[6] = (const float*)d_in[9];  w9.p[7] = (const float*)d_in[10];
    w9.p[8] = (const float*)d_in[11];

    short* XP   = (short*)d_ws;            // x packed (and t1p in fallback)
    short* PA   = XP + PADE;               // x1p -> xsp
    float* F1   = (float*)(PA + PADE);     // x1 + y1+y2+y3
    short* WPK  = (short*)(F1 + TOT);
    float* BIAS = (float*)(WPK + WPK_TOT); // 48 floats (pad to 64)
    short* T1P  = (short*)(BIAS + 64);     // t1p (merged path only)
    float* F2   = (float*)d_out;           // x2..x7 sum scratch

    const size_t need = ((size_t)(3 * PADE + WPK_TOT) * 2)
                      + (size_t)TOT * 4 + 64 * 4;
    const bool merged = ws_size >= need;

    const dim3 blk(256);
    const dim3 pgrid(DP_ * HP_);           // 17956
    const dim3 sgrid(DD * 8);              // 1024 (small conv, final)
    const dim3 tgrid(512);                 // tile convs

    if (merged) pack_x2<<<pgrid, blk, 0, stream>>>(x, XP, PA, T1P);
    else        pack_x<<<pgrid, blk, 0, stream>>>(x, XP, PA);
    pack_small<<<dim3(6), blk, 0, stream>>>(w1, wch, WPK);
    pack_fused<<<dim3(441), blk, 0, stream>>>(w9, w1, bng, bnb, bnm, bnv, WPK, BIAS);

    // PA = x1p = bf16(cbn(x, w1, 0))
    conv_mfma<3,3,1,9,false,1><<<sgrid, blk, 0, stream>>>(
        XP, WPK + OFF_W1, bng, bnb, bnm, bnv, 0, nullptr, PA);

    if (merged) {
        // One dispatch: G0 (F2 = x2+x3+x4, t1p -> T1P) + G2 (F1 = x1+y1+y2+y3)
        conv_dual<<<dim3(1024), blk, 0, stream>>>(
            PA, WPK + OFF_G0, BIAS + 0, F2, T1P,
            XP, WPK + OFF_G2, BIAS + 32, F1);
        // PA <- xsp = relu(x1p + F2 + (x5+x6+x7))  (G1 over t1p)
        conv_tile_lds<3><<<tgrid, blk, 0, stream>>>(T1P, WPK + OFF_G1, BIAS + 16, F2, PA);
    } else {
        conv_tile_lds<0><<<tgrid, blk, 0, stream>>>(XP, WPK + OFF_G2, BIAS + 32, F1, nullptr);
        conv_tile_lds<2><<<tgrid, blk, 0, stream>>>(PA, WPK + OFF_G0, BIAS + 0, F2, XP);
        conv_tile_lds<3><<<tgrid, blk, 0, stream>>>(XP, WPK + OFF_G1, BIAS + 16, F2, PA);
    }
    // out = relu(F1 + conv1x1(xs, wch)), transposed store
    final_conv<<<sgrid, blk, 0, stream>>>(PA, WPK + OFF_WCH, F1, (float*)d_out);

    (void)in_sizes; (void)n_in; (void)out_size; (void)ws_size;
}